// Round 1
// baseline (922.747 us; speedup 1.0000x reference)
//
#include <hip/hip_runtime.h>
#include <hip/hip_bf16.h>
#include <math.h>

#define N_NODES 50000
#define NE      800000
#define ETOT    (NE + N_NODES)   // edges + self loops = 850000
#define F       128              // F_in == H*C
#define NHEAD   4
#define NEG     0.2f

#define SCAN_B 256
#define NBLK   ((N_NODES + SCAN_B - 1) / SCAN_B)   // 196

// ---------------- CSR build ----------------

__global__ void k_zero(int* __restrict__ p, int n) {
    int i = blockIdx.x * blockDim.x + threadIdx.x;
    if (i < n) p[i] = 0;
}

__global__ void k_deg(const int* __restrict__ ei, int* __restrict__ deg) {
    int i = blockIdx.x * blockDim.x + threadIdx.x;
    if (i < ETOT) {
        int d = (i < NE) ? ei[NE + i] : (i - NE);   // edge_index[1][i] or self loop
        atomicAdd(&deg[d], 1);
    }
}

__global__ void k_scan1(const int* __restrict__ deg, int* __restrict__ bsum) {
    __shared__ int sm[SCAN_B];
    int i = blockIdx.x * SCAN_B + threadIdx.x;
    sm[threadIdx.x] = (i < N_NODES) ? deg[i] : 0;
    __syncthreads();
    for (int s = SCAN_B / 2; s > 0; s >>= 1) {
        if (threadIdx.x < s) sm[threadIdx.x] += sm[threadIdx.x + s];
        __syncthreads();
    }
    if (threadIdx.x == 0) bsum[blockIdx.x] = sm[0];
}

__global__ void k_scan2(int* __restrict__ bsum) {   // 1 block: exclusive scan of NBLK sums
    __shared__ int sm[SCAN_B];
    int t = threadIdx.x;
    int v = (t < NBLK) ? bsum[t] : 0;
    sm[t] = v; __syncthreads();
    for (int s = 1; s < SCAN_B; s <<= 1) {
        int a = (t >= s) ? sm[t - s] : 0;
        __syncthreads();
        sm[t] += a;
        __syncthreads();
    }
    if (t < NBLK) bsum[t] = sm[t] - v;  // exclusive
}

__global__ void k_scan3(const int* __restrict__ deg, const int* __restrict__ bsum,
                        int* __restrict__ rowptr, int* __restrict__ cursor) {
    __shared__ int sm[SCAN_B];
    int t = threadIdx.x;
    int i = blockIdx.x * SCAN_B + t;
    int v = (i < N_NODES) ? deg[i] : 0;
    sm[t] = v; __syncthreads();
    for (int s = 1; s < SCAN_B; s <<= 1) {
        int a = (t >= s) ? sm[t - s] : 0;
        __syncthreads();
        sm[t] += a;
        __syncthreads();
    }
    int excl = sm[t] - v + bsum[blockIdx.x];
    if (i < N_NODES) { rowptr[i] = excl; cursor[i] = excl; }
    if (i == N_NODES - 1) rowptr[N_NODES] = excl + v;
}

__global__ void k_fill(const int* __restrict__ ei, int* __restrict__ cursor,
                       int* __restrict__ col) {
    int i = blockIdx.x * blockDim.x + threadIdx.x;
    if (i < ETOT) {
        int s, d;
        if (i < NE) { s = ei[i]; d = ei[NE + i]; }
        else        { s = i - NE; d = s; }
        int pos = atomicAdd(&cursor[d], 1);
        col[pos] = s;
    }
}

// ---------------- GEMM: C[n][j] = sum_k X[n][k] * W[j][k] ----------------
// 64 nodes/block, 256 threads, each thread 4 nodes x 8 j (j = tx + jj*16)

#define GM 64
#define KT 32
#define LPAD 36   // LDS row stride in floats (16B-aligned, conflict-free patterns)

__global__ __launch_bounds__(256) void k_gemm(const float* __restrict__ X,
                                              const float* __restrict__ W,
                                              float* __restrict__ Cmat) {
    __shared__ float Xs[GM * LPAD];
    __shared__ float Wsh[F * LPAD];
    int tid = threadIdx.x;
    int tx = tid & 15;    // j = tx + jj*16
    int ty = tid >> 4;    // nodes ty*4 .. ty*4+3
    int bm = blockIdx.x * GM;

    float acc[4][8];
#pragma unroll
    for (int i = 0; i < 4; i++)
#pragma unroll
        for (int j = 0; j < 8; j++) acc[i][j] = 0.f;

    for (int k0 = 0; k0 < F; k0 += KT) {
        // stage X tile: 64x32 floats = 512 float4, 2 per thread
#pragma unroll
        for (int u = 0; u < 2; u++) {
            int f4 = tid * 2 + u;
            int r = f4 >> 3, c4 = f4 & 7;
            int gr = bm + r;
            float4 v = make_float4(0.f, 0.f, 0.f, 0.f);
            if (gr < N_NODES) v = *(const float4*)&X[gr * F + k0 + c4 * 4];
            *(float4*)&Xs[r * LPAD + c4 * 4] = v;
        }
        // stage W tile: 128x32 floats = 1024 float4, 4 per thread
#pragma unroll
        for (int u = 0; u < 4; u++) {
            int f4 = tid * 4 + u;
            int r = f4 >> 3, c4 = f4 & 7;
            *(float4*)&Wsh[r * LPAD + c4 * 4] = *(const float4*)&W[r * F + k0 + c4 * 4];
        }
        __syncthreads();

#pragma unroll
        for (int kk = 0; kk < KT; kk += 4) {
            float4 xv[4], wv[8];
#pragma unroll
            for (int i = 0; i < 4; i++) xv[i] = *(float4*)&Xs[(ty * 4 + i) * LPAD + kk];
#pragma unroll
            for (int j = 0; j < 8; j++) wv[j] = *(float4*)&Wsh[(tx + j * 16) * LPAD + kk];
#pragma unroll
            for (int i = 0; i < 4; i++)
#pragma unroll
                for (int j = 0; j < 8; j++)
                    acc[i][j] += xv[i].x * wv[j].x + xv[i].y * wv[j].y
                               + xv[i].z * wv[j].z + xv[i].w * wv[j].w;
        }
        __syncthreads();
    }

#pragma unroll
    for (int i = 0; i < 4; i++) {
        int n = bm + ty * 4 + i;
        if (n < N_NODES) {
#pragma unroll
            for (int j = 0; j < 8; j++) Cmat[n * F + tx + j * 16] = acc[i][j];
        }
    }
}

// ---------------- per-node attention logits ----------------
// asrc[n][h] = sum_c h[n][h][c]*a_src[h][c]; block = 128 threads = one node

__global__ void k_alpha(const float* __restrict__ h, const float* __restrict__ a_s,
                        const float* __restrict__ a_d, float* __restrict__ asrc,
                        float* __restrict__ adst) {
    int n = blockIdx.x;
    int t = threadIdx.x;
    float hv = h[n * F + t];
    float ps = hv * a_s[t];
    float pd = hv * a_d[t];
#pragma unroll
    for (int s = 16; s > 0; s >>= 1) {   // butterfly within 32-lane head group
        ps += __shfl_xor(ps, s, 32);
        pd += __shfl_xor(pd, s, 32);
    }
    if ((t & 31) == 0) {
        asrc[n * NHEAD + (t >> 5)] = ps;
        adst[n * NHEAD + (t >> 5)] = pd;
    }
}

// ---------------- fused softmax + aggregate, one wave per dst node ----------------

__global__ __launch_bounds__(256) void k_aggr(const float* __restrict__ h,
                                              const float* __restrict__ asrc,
                                              const float* __restrict__ adst,
                                              const int* __restrict__ rowptr,
                                              const int* __restrict__ col,
                                              const float* __restrict__ bias,
                                              float* __restrict__ xout) {
    int wave = threadIdx.x >> 6;
    int lane = threadIdx.x & 63;
    int n = blockIdx.x * 4 + wave;
    if (n >= N_NODES) return;
    int head = lane >> 4;                // lane owns channels 2*lane, 2*lane+1
    int beg = rowptr[n], end = rowptr[n + 1];
    float ad = adst[n * NHEAD + head];

    // pass A: per-head max of leaky_relu(e) (all lanes of a head group compute same)
    float m = -1e30f;
    for (int p = beg; p < end; p++) {
        int s = col[p];
        float e = asrc[s * NHEAD + head] + ad;
        e = (e > 0.f) ? e : NEG * e;
        m = fmaxf(m, e);
    }
    // pass B: w = exp(e-m); accumulate sum and weighted features
    float ssum = 0.f, accx = 0.f, accy = 0.f;
    for (int p = beg; p < end; p++) {
        int s = col[p];
        float e = asrc[s * NHEAD + head] + ad;
        e = (e > 0.f) ? e : NEG * e;
        float w = __expf(e - m);
        ssum += w;
        float2 hv = *(const float2*)&h[s * F + lane * 2];
        accx += w * hv.x;
        accy += w * hv.y;
    }
    float inv = 1.f / (ssum + 1e-16f);
    float2 b2 = *(const float2*)&bias[lane * 2];
    float ox = fmaxf(accx * inv + b2.x, 0.f);   // + conv bias, relu
    float oy = fmaxf(accy * inv + b2.y, 0.f);
    *(float2*)&xout[n * F + lane * 2] = make_float2(ox, oy);
}

// ---------------- final linear 128 -> 32 ----------------

__global__ void k_fc(const float* __restrict__ X, const float* __restrict__ Wf,
                     const float* __restrict__ bf, float* __restrict__ out) {
    int idx = blockIdx.x * blockDim.x + threadIdx.x;
    int n = idx >> 5, o = idx & 31;
    if (n >= N_NODES) return;
    const float* xr = &X[n * F];
    const float* wr = &Wf[o * F];
    float acc = 0.f;
#pragma unroll
    for (int k = 0; k < F; k += 4) {
        float4 xv = *(const float4*)&xr[k];
        float4 wv = *(const float4*)&wr[k];
        acc += xv.x * wv.x + xv.y * wv.y + xv.z * wv.z + xv.w * wv.w;
    }
    out[idx] = acc + bf[o];
}

// ---------------- launch ----------------

extern "C" void kernel_launch(void* const* d_in, const int* in_sizes, int n_in,
                              void* d_out, int out_size, void* d_ws, size_t ws_size,
                              hipStream_t stream) {
    const float* x      = (const float*)d_in[0];   // [N,128]
    const float* Ws     = (const float*)d_in[1];   // [3,128,128]
    const float* a_src  = (const float*)d_in[2];   // [3,4,32]
    const float* a_dst  = (const float*)d_in[3];   // [3,4,32]
    const float* cbias  = (const float*)d_in[4];   // [3,128]
    const float* Wf     = (const float*)d_in[5];   // [32,128]
    const float* bf     = (const float*)d_in[6];   // [32]
    const int*   ei     = (const int*)d_in[7];     // [2,800000]
    float* out = (float*)d_out;

    // workspace carve-up (256B aligned)
    char* p = (char*)d_ws;
    auto carve = [&](size_t bytes) {
        char* r = p;
        p += (bytes + 255) & ~(size_t)255;
        return r;
    };
    float* xA   = (float*)carve((size_t)N_NODES * F * 4);
    float* xB   = (float*)carve((size_t)N_NODES * F * 4);
    float* hbuf = (float*)carve((size_t)N_NODES * F * 4);
    float* asrc = (float*)carve((size_t)N_NODES * NHEAD * 4);
    float* adst = (float*)carve((size_t)N_NODES * NHEAD * 4);
    int* deg    = (int*)carve((size_t)N_NODES * 4);
    int* rowptr = (int*)carve((size_t)(N_NODES + 1) * 4);
    int* cursor = (int*)carve((size_t)N_NODES * 4);
    int* bsum   = (int*)carve((size_t)SCAN_B * 4);
    int* col    = (int*)carve((size_t)ETOT * 4);

    // ---- CSR build (dst-sorted adjacency) ----
    k_zero<<<(N_NODES + 255) / 256, 256, 0, stream>>>(deg, N_NODES);
    k_deg<<<(ETOT + 255) / 256, 256, 0, stream>>>(ei, deg);
    k_scan1<<<NBLK, SCAN_B, 0, stream>>>(deg, bsum);
    k_scan2<<<1, SCAN_B, 0, stream>>>(bsum);
    k_scan3<<<NBLK, SCAN_B, 0, stream>>>(deg, bsum, rowptr, cursor);
    k_fill<<<(ETOT + 255) / 256, 256, 0, stream>>>(ei, cursor, col);

    // ---- 3 GAT layers ----
    const float* xin = x;
    float* bufs[2] = {xA, xB};
    for (int l = 0; l < 3; l++) {
        k_gemm<<<(N_NODES + GM - 1) / GM, 256, 0, stream>>>(xin, Ws + (size_t)l * F * F, hbuf);
        k_alpha<<<N_NODES, 128, 0, stream>>>(hbuf, a_src + l * F, a_dst + l * F, asrc, adst);
        k_aggr<<<(N_NODES + 3) / 4, 256, 0, stream>>>(hbuf, asrc, adst, rowptr, col,
                                                      cbias + l * F, bufs[l & 1]);
        xin = bufs[l & 1];
    }

    // ---- final linear ----
    k_fc<<<(N_NODES * 32 + 255) / 256, 256, 0, stream>>>(xin, Wf, bf, out);
}

// Round 2
// 731.089 us; speedup vs baseline: 1.2622x; 1.2622x over previous
//
#include <hip/hip_runtime.h>
#include <hip/hip_bf16.h>
#include <math.h>

#define N_NODES 50000
#define NE      800000
#define ETOT    (NE + N_NODES)   // edges + self loops = 850000
#define F       128              // F_in == H*C
#define NHEAD   4
#define NEG     0.2f

#define SCAN_B 256
#define NBLK   ((N_NODES + SCAN_B - 1) / SCAN_B)   // 196

// ---------------- CSR build ----------------

__global__ void k_zero(int* __restrict__ p, int n) {
    int i = blockIdx.x * blockDim.x + threadIdx.x;
    if (i < n) p[i] = 0;
}

__global__ void k_deg(const int* __restrict__ ei, int* __restrict__ deg) {
    int i = blockIdx.x * blockDim.x + threadIdx.x;
    if (i < ETOT) {
        int d = (i < NE) ? ei[NE + i] : (i - NE);
        atomicAdd(&deg[d], 1);
    }
}

__global__ void k_scan1(const int* __restrict__ deg, int* __restrict__ bsum) {
    __shared__ int sm[SCAN_B];
    int i = blockIdx.x * SCAN_B + threadIdx.x;
    sm[threadIdx.x] = (i < N_NODES) ? deg[i] : 0;
    __syncthreads();
    for (int s = SCAN_B / 2; s > 0; s >>= 1) {
        if (threadIdx.x < s) sm[threadIdx.x] += sm[threadIdx.x + s];
        __syncthreads();
    }
    if (threadIdx.x == 0) bsum[blockIdx.x] = sm[0];
}

__global__ void k_scan2(int* __restrict__ bsum) {
    __shared__ int sm[SCAN_B];
    int t = threadIdx.x;
    int v = (t < NBLK) ? bsum[t] : 0;
    sm[t] = v; __syncthreads();
    for (int s = 1; s < SCAN_B; s <<= 1) {
        int a = (t >= s) ? sm[t - s] : 0;
        __syncthreads();
        sm[t] += a;
        __syncthreads();
    }
    if (t < NBLK) bsum[t] = sm[t] - v;  // exclusive
}

__global__ void k_scan3(const int* __restrict__ deg, const int* __restrict__ bsum,
                        int* __restrict__ rowptr, int* __restrict__ cursor) {
    __shared__ int sm[SCAN_B];
    int t = threadIdx.x;
    int i = blockIdx.x * SCAN_B + t;
    int v = (i < N_NODES) ? deg[i] : 0;
    sm[t] = v; __syncthreads();
    for (int s = 1; s < SCAN_B; s <<= 1) {
        int a = (t >= s) ? sm[t - s] : 0;
        __syncthreads();
        sm[t] += a;
        __syncthreads();
    }
    int excl = sm[t] - v + bsum[blockIdx.x];
    if (i < N_NODES) { rowptr[i] = excl; cursor[i] = excl; }
    if (i == N_NODES - 1) rowptr[N_NODES] = excl + v;
}

__global__ void k_fill(const int* __restrict__ ei, int* __restrict__ cursor,
                       int* __restrict__ col) {
    int i = blockIdx.x * blockDim.x + threadIdx.x;
    if (i < ETOT) {
        int s, d;
        if (i < NE) { s = ei[i]; d = ei[NE + i]; }
        else        { s = i - NE; d = s; }
        int pos = atomicAdd(&cursor[d], 1);
        col[pos] = s;
    }
}

// ---------------- GEMM + fused alpha: h = X @ W^T, asrc/adst per node/head ----
// 128 nodes/block, 256 threads, each thread 8 nodes x 8 j (j = tx + jj*16)

#define GM 128
#define KT 32
#define LPAD 36

__global__ __launch_bounds__(256) void k_gemm(const float* __restrict__ X,
                                              const float* __restrict__ W,
                                              const float* __restrict__ a_s,
                                              const float* __restrict__ a_d,
                                              float* __restrict__ hout,
                                              float* __restrict__ asrc,
                                              float* __restrict__ adst) {
    __shared__ float Xs[GM * LPAD];
    __shared__ float Wsh[F * LPAD];
    int tid = threadIdx.x;
    int tx = tid & 15;    // j = tx + jj*16
    int ty = tid >> 4;    // nodes ty*8 .. ty*8+7
    int bm = blockIdx.x * GM;

    float acc[8][8];
#pragma unroll
    for (int i = 0; i < 8; i++)
#pragma unroll
        for (int j = 0; j < 8; j++) acc[i][j] = 0.f;

    for (int k0 = 0; k0 < F; k0 += KT) {
        // stage X tile: 128x32 floats = 1024 float4, 4 per thread
#pragma unroll
        for (int u = 0; u < 4; u++) {
            int f4 = tid + 256 * u;
            int r = f4 >> 3, c4 = f4 & 7;
            int gr = bm + r;
            float4 v = make_float4(0.f, 0.f, 0.f, 0.f);
            if (gr < N_NODES) v = *(const float4*)&X[(size_t)gr * F + k0 + c4 * 4];
            *(float4*)&Xs[r * LPAD + c4 * 4] = v;
        }
        // stage W tile: 128x32 floats
#pragma unroll
        for (int u = 0; u < 4; u++) {
            int f4 = tid + 256 * u;
            int r = f4 >> 3, c4 = f4 & 7;
            *(float4*)&Wsh[r * LPAD + c4 * 4] = *(const float4*)&W[r * F + k0 + c4 * 4];
        }
        __syncthreads();

#pragma unroll
        for (int kk = 0; kk < KT; kk += 4) {
            float4 xv[8], wv[8];
#pragma unroll
            for (int i = 0; i < 8; i++) xv[i] = *(float4*)&Xs[(ty * 8 + i) * LPAD + kk];
#pragma unroll
            for (int j = 0; j < 8; j++) wv[j] = *(float4*)&Wsh[(tx + j * 16) * LPAD + kk];
#pragma unroll
            for (int i = 0; i < 8; i++)
#pragma unroll
                for (int j = 0; j < 8; j++)
                    acc[i][j] += xv[i].x * wv[j].x + xv[i].y * wv[j].y
                               + xv[i].z * wv[j].z + xv[i].w * wv[j].w;
        }
        __syncthreads();
    }

    // epilogue: store h + fused per-node attention logits
    float as_v[8], ad_v[8];
#pragma unroll
    for (int jj = 0; jj < 8; jj++) {
        as_v[jj] = a_s[tx + jj * 16];
        ad_v[jj] = a_d[tx + jj * 16];
    }
#pragma unroll
    for (int i = 0; i < 8; i++) {
        int n = bm + ty * 8 + i;
        bool ok = (n < N_NODES);
        if (ok) {
#pragma unroll
            for (int jj = 0; jj < 8; jj++) hout[(size_t)n * F + tx + jj * 16] = acc[i][jj];
        }
        float ps[4], pd[4];
#pragma unroll
        for (int hh = 0; hh < 4; hh++) {
            ps[hh] = acc[i][2 * hh] * as_v[2 * hh] + acc[i][2 * hh + 1] * as_v[2 * hh + 1];
            pd[hh] = acc[i][2 * hh] * ad_v[2 * hh] + acc[i][2 * hh + 1] * ad_v[2 * hh + 1];
        }
#pragma unroll
        for (int s = 1; s < 16; s <<= 1) {
#pragma unroll
            for (int hh = 0; hh < 4; hh++) {
                ps[hh] += __shfl_xor(ps[hh], s);
                pd[hh] += __shfl_xor(pd[hh], s);
            }
        }
        if (ok && tx == 0) {
            *(float4*)&asrc[n * 4] = make_float4(ps[0], ps[1], ps[2], ps[3]);
            *(float4*)&adst[n * 4] = make_float4(pd[0], pd[1], pd[2], pd[3]);
        }
    }
}

// ---------------- fused softmax + aggregate, one wave per dst node ----------------
// Chunked online softmax: coalesced col load + lane-parallel logits + LDS-parked
// weights, then a pipelined feature gather with all addresses pre-resolved.

__device__ __forceinline__ float selh(float4 v, int h) {
    float r = v.x;
    r = (h == 1) ? v.y : r;
    r = (h == 2) ? v.z : r;
    r = (h == 3) ? v.w : r;
    return r;
}

__global__ __launch_bounds__(256) void k_aggr(const float* __restrict__ h,
                                              const float* __restrict__ asrc,
                                              const float* __restrict__ adst,
                                              const int* __restrict__ rowptr,
                                              const int* __restrict__ col,
                                              const float* __restrict__ bias,
                                              float* __restrict__ xout) {
    __shared__ int   scol[4][64];
    __shared__ float sw[4][64 * 4];
    int wave = threadIdx.x >> 6;
    int lane = threadIdx.x & 63;
    int n = blockIdx.x * 4 + wave;
    if (n >= N_NODES) return;
    int head = lane >> 4;                // lane owns channels 2*lane, 2*lane+1
    int beg = rowptr[n], end = rowptr[n + 1];
    float4 ad4 = *(const float4*)&adst[n * 4];

    float4 m4 = make_float4(-1e30f, -1e30f, -1e30f, -1e30f);
    float4 s4 = make_float4(0.f, 0.f, 0.f, 0.f);
    float accx = 0.f, accy = 0.f;

    for (int base = beg; base < end; base += 64) {
        int cnt = end - base; if (cnt > 64) cnt = 64;
        int sidx = 0;
        float4 e4 = make_float4(-1e30f, -1e30f, -1e30f, -1e30f);
        if (lane < cnt) {
            sidx = col[base + lane];
            float4 av = *(const float4*)&asrc[sidx * 4];
            float ex = av.x + ad4.x, ey = av.y + ad4.y,
                  ez = av.z + ad4.z, ew = av.w + ad4.w;
            e4.x = (ex > 0.f) ? ex : NEG * ex;
            e4.y = (ey > 0.f) ? ey : NEG * ey;
            e4.z = (ez > 0.f) ? ez : NEG * ez;
            e4.w = (ew > 0.f) ? ew : NEG * ew;
        }
        scol[wave][lane] = sidx;
        // chunk max (butterfly over the wave)
        float4 M4 = e4;
#pragma unroll
        for (int s = 1; s < 64; s <<= 1) {
            M4.x = fmaxf(M4.x, __shfl_xor(M4.x, s));
            M4.y = fmaxf(M4.y, __shfl_xor(M4.y, s));
            M4.z = fmaxf(M4.z, __shfl_xor(M4.z, s));
            M4.w = fmaxf(M4.w, __shfl_xor(M4.w, s));
        }
        float4 nm;
        nm.x = fmaxf(m4.x, M4.x); nm.y = fmaxf(m4.y, M4.y);
        nm.z = fmaxf(m4.z, M4.z); nm.w = fmaxf(m4.w, M4.w);
        // rescale running state
        float4 sc;
        sc.x = __expf(m4.x - nm.x); sc.y = __expf(m4.y - nm.y);
        sc.z = __expf(m4.z - nm.z); sc.w = __expf(m4.w - nm.w);
        s4.x *= sc.x; s4.y *= sc.y; s4.z *= sc.z; s4.w *= sc.w;
        float rs = selh(sc, head);
        accx *= rs; accy *= rs;
        // weights for this chunk
        float4 w4;
        w4.x = (lane < cnt) ? __expf(e4.x - nm.x) : 0.f;
        w4.y = (lane < cnt) ? __expf(e4.y - nm.y) : 0.f;
        w4.z = (lane < cnt) ? __expf(e4.z - nm.z) : 0.f;
        w4.w = (lane < cnt) ? __expf(e4.w - nm.w) : 0.f;
        *(float4*)&sw[wave][lane * 4] = w4;
        // chunk sum
        float4 S4 = w4;
#pragma unroll
        for (int s = 1; s < 64; s <<= 1) {
            S4.x += __shfl_xor(S4.x, s);
            S4.y += __shfl_xor(S4.y, s);
            S4.z += __shfl_xor(S4.z, s);
            S4.w += __shfl_xor(S4.w, s);
        }
        s4.x += S4.x; s4.y += S4.y; s4.z += S4.z; s4.w += S4.w;
        m4 = nm;
        // pipelined feature gather: addresses all resident in LDS
#pragma unroll 4
        for (int p = 0; p < cnt; p++) {
            int s = scol[wave][p];
            float wgt = sw[wave][p * 4 + head];
            float2 hv = *(const float2*)&h[(size_t)s * F + lane * 2];
            accx = fmaf(wgt, hv.x, accx);
            accy = fmaf(wgt, hv.y, accy);
        }
    }

    float ssum = selh(s4, head);
    float inv = 1.f / (ssum + 1e-16f);
    float2 b2 = *(const float2*)&bias[lane * 2];
    float ox = fmaxf(fmaf(accx, inv, b2.x), 0.f);
    float oy = fmaxf(fmaf(accy, inv, b2.y), 0.f);
    *(float2*)&xout[(size_t)n * F + lane * 2] = make_float2(ox, oy);
}

// ---------------- final linear 128 -> 32 ----------------

__global__ void k_fc(const float* __restrict__ X, const float* __restrict__ Wf,
                     const float* __restrict__ bf, float* __restrict__ out) {
    int idx = blockIdx.x * blockDim.x + threadIdx.x;
    int n = idx >> 5, o = idx & 31;
    if (n >= N_NODES) return;
    const float* xr = &X[(size_t)n * F];
    const float* wr = &Wf[o * F];
    float acc = 0.f;
#pragma unroll
    for (int k = 0; k < F; k += 4) {
        float4 xv = *(const float4*)&xr[k];
        float4 wv = *(const float4*)&wr[k];
        acc += xv.x * wv.x + xv.y * wv.y + xv.z * wv.z + xv.w * wv.w;
    }
    out[idx] = acc + bf[o];
}

// ---------------- launch ----------------

extern "C" void kernel_launch(void* const* d_in, const int* in_sizes, int n_in,
                              void* d_out, int out_size, void* d_ws, size_t ws_size,
                              hipStream_t stream) {
    const float* x      = (const float*)d_in[0];   // [N,128]
    const float* Ws     = (const float*)d_in[1];   // [3,128,128]
    const float* a_src  = (const float*)d_in[2];   // [3,4,32]
    const float* a_dst  = (const float*)d_in[3];   // [3,4,32]
    const float* cbias  = (const float*)d_in[4];   // [3,128]
    const float* Wf     = (const float*)d_in[5];   // [32,128]
    const float* bf     = (const float*)d_in[6];   // [32]
    const int*   ei     = (const int*)d_in[7];     // [2,800000]
    float* out = (float*)d_out;

    char* p = (char*)d_ws;
    auto carve = [&](size_t bytes) {
        char* r = p;
        p += (bytes + 255) & ~(size_t)255;
        return r;
    };
    float* xA   = (float*)carve((size_t)N_NODES * F * 4);
    float* xB   = (float*)carve((size_t)N_NODES * F * 4);
    float* hbuf = (float*)carve((size_t)N_NODES * F * 4);
    float* asrc = (float*)carve((size_t)N_NODES * NHEAD * 4);
    float* adst = (float*)carve((size_t)N_NODES * NHEAD * 4);
    int* deg    = (int*)carve((size_t)N_NODES * 4);
    int* rowptr = (int*)carve((size_t)(N_NODES + 1) * 4);
    int* cursor = (int*)carve((size_t)N_NODES * 4);
    int* bsum   = (int*)carve((size_t)SCAN_B * 4);
    int* col    = (int*)carve((size_t)ETOT * 4);

    // ---- CSR build (dst-sorted adjacency) ----
    k_zero<<<(N_NODES + 255) / 256, 256, 0, stream>>>(deg, N_NODES);
    k_deg<<<(ETOT + 255) / 256, 256, 0, stream>>>(ei, deg);
    k_scan1<<<NBLK, SCAN_B, 0, stream>>>(deg, bsum);
    k_scan2<<<1, SCAN_B, 0, stream>>>(bsum);
    k_scan3<<<NBLK, SCAN_B, 0, stream>>>(deg, bsum, rowptr, cursor);
    k_fill<<<(ETOT + 255) / 256, 256, 0, stream>>>(ei, cursor, col);

    // ---- 3 GAT layers ----
    const float* xin = x;
    float* bufs[2] = {xA, xB};
    for (int l = 0; l < 3; l++) {
        k_gemm<<<(N_NODES + GM - 1) / GM, 256, 0, stream>>>(
            xin, Ws + (size_t)l * F * F, a_src + l * F, a_dst + l * F,
            hbuf, asrc, adst);
        k_aggr<<<(N_NODES + 3) / 4, 256, 0, stream>>>(hbuf, asrc, adst, rowptr, col,
                                                      cbias + l * F, bufs[l & 1]);
        xin = bufs[l & 1];
    }

    // ---- final linear ----
    k_fc<<<(N_NODES * 32 + 255) / 256, 256, 0, stream>>>(xin, Wf, bf, out);
}